// Round 5
// baseline (347.779 us; speedup 1.0000x reference)
//
#include <hip/hip_runtime.h>

#define HH 512
#define WW 512
#define NB 4

// ---------------- Stage 1: 11x11 convs (1->8, pos & neg) + spike/WTA logic ----------------
// P and N convs run as two sequential passes so register liveness stays ~55 VGPRs
// (acc[8][4]=32 + a[16]); each pass's 32 spikes compress into one u32 bitmask.
#define K1 11
#define PAD1 5
#define T1 32
#define IN1 42        // 32 + 10 halo
#define S1 44         // LDS row stride (floats); lane starts (44*ly+4*lx)%32 hit all 8 quads

__global__ __launch_bounds__(256, 4) void stage1_kernel(
    const float* __restrict__ inp, const float* __restrict__ Wb,
    unsigned char* __restrict__ border)
{
    __shared__ __align__(16) float s0[IN1 * S1];
    __shared__ __align__(16) float s1[IN1 * S1];

    const int b   = blockIdx.z;
    const int tx0 = blockIdx.x * T1;
    const int ty0 = blockIdx.y * T1;
    const float* in0 = inp + ((size_t)b * 2 + 0) * (HH * WW);
    const float* in1 = inp + ((size_t)b * 2 + 1) * (HH * WW);

    for (int i = threadIdx.x; i < IN1 * IN1; i += 256) {
        int iy = i / IN1, ix = i - iy * IN1;
        int gy = ty0 + iy - PAD1, gx = tx0 + ix - PAD1;
        bool ok = (gy >= 0) & (gy < HH) & (gx >= 0) & (gx < WW);
        int idx = gy * WW + gx;
        s0[iy * S1 + ix] = ok ? in0[idx] : 0.f;
        s1[iy * S1 + ix] = ok ? in1[idx] : 0.f;
    }
    __syncthreads();

    const int lx = threadIdx.x & 7;   // 8 groups of 4 px -> 32 wide
    const int ly = threadIdx.x >> 3;  // 32 rows
    const int px = lx * 4;
    const int py = ly;

    // ---- pass P: conv of s0, all 8 channels, spikes -> bitP ----
    unsigned bitP = 0;
    {
        float acc[8][4];
        #pragma unroll
        for (int c = 0; c < 8; c++)
            #pragma unroll
            for (int p = 0; p < 4; p++) acc[c][p] = 0.f;
        #pragma unroll 1
        for (int ky = 0; ky < K1; ky++) {
            const float4* rp = (const float4*)&s0[(py + ky) * S1 + px];
            float a[16];
            #pragma unroll
            for (int r = 0; r < 4; r++) *(float4*)&a[4 * r] = rp[r];
            #pragma unroll
            for (int c = 0; c < 8; c++) {
                const float* wr = Wb + c * (K1 * K1) + ky * K1;  // uniform -> s_load
                #pragma unroll
                for (int kx = 0; kx < K1; kx++) {
                    const float wv = wr[kx];
                    #pragma unroll
                    for (int p = 0; p < 4; p++)
                        acc[c][p] = fmaf(a[kx + p], wv, acc[c][p]);
                }
            }
        }
        #pragma unroll
        for (int c = 0; c < 8; c++)
            #pragma unroll
            for (int p = 0; p < 4; p++)
                bitP |= (acc[c][p] >= 1.f ? 1u : 0u) << (c * 4 + p);
    }
    // ---- pass N: conv of s1 ----
    unsigned bitN = 0;
    {
        float acc[8][4];
        #pragma unroll
        for (int c = 0; c < 8; c++)
            #pragma unroll
            for (int p = 0; p < 4; p++) acc[c][p] = 0.f;
        #pragma unroll 1
        for (int ky = 0; ky < K1; ky++) {
            const float4* rp = (const float4*)&s1[(py + ky) * S1 + px];
            float a[16];
            #pragma unroll
            for (int r = 0; r < 4; r++) *(float4*)&a[4 * r] = rp[r];
            #pragma unroll
            for (int c = 0; c < 8; c++) {
                const float* wr = Wb + c * (K1 * K1) + ky * K1;
                #pragma unroll
                for (int kx = 0; kx < K1; kx++) {
                    const float wv = wr[kx];
                    #pragma unroll
                    for (int p = 0; p < 4; p++)
                        acc[c][p] = fmaf(a[kx + p], wv, acc[c][p]);
                }
            }
        }
        #pragma unroll
        for (int c = 0; c < 8; c++)
            #pragma unroll
            for (int p = 0; p < 4; p++)
                bitN |= (acc[c][p] >= 1.f ? 1u : 0u) << (c * 4 + p);
    }

    // ---- spike / WTA logic from bitmasks ----
    const int gy = ty0 + py;
    const int gxbase = tx0 + px;

    float vm[4];
    #pragma unroll
    for (int p = 0; p < 4; p++)
        vm[p] = s0[(py + PAD1) * S1 + px + PAD1 + p]
              + s1[(py + PAD1) * S1 + px + PAD1 + p];

    float b13[4][4], b24[4][4];       // [o][p]
    #pragma unroll
    for (int o = 0; o < 4; o++) {
        #pragma unroll
        for (int p = 0; p < 4; p++) {
            float pe = (float)((bitP >> (8 * o + p))     & 1u);
            float po = (float)((bitP >> (8 * o + 4 + p)) & 1u);
            float ne = (float)((bitN >> (8 * o + p))     & 1u);
            float no = (float)((bitN >> (8 * o + 4 + p)) & 1u);
            float sa = (vm[p] * (pe - 1.5f * no) >= 1.f) ? 1.f : 0.f;
            float sb = (vm[p] * (ne - 1.5f * po) >= 1.f) ? 1.f : 0.f;
            b13[o][p] = sa + sb;
            float sc = (vm[p] * (po - 1.5f * ne) >= 1.f) ? 1.f : 0.f;
            float sd = (vm[p] * (no - 1.5f * pe) >= 1.f) ? 1.f : 0.f;
            b24[o][p] = sc + sd;
        }
    }
    float mxp[4];
    #pragma unroll
    for (int p = 0; p < 4; p++) {
        float m = 0.f;
        #pragma unroll
        for (int o = 0; o < 4; o++) m = fmaxf(m, fabsf(b13[o][p] - b24[o][p]));
        mxp[p] = m;
    }
    #pragma unroll
    for (int o = 0; o < 4; o++) {
        unsigned w0 = 0, w1 = 0, w2 = 0, w3 = 0;
        #pragma unroll
        for (int p = 0; p < 4; p++) {
            float d   = b13[o][p] - b24[o][p];
            float wta = (fabsf(d) == mxp[p]) ? 1.f : 0.f;
            float b1p = (wta * d >= 1.f)    ? 1.f : 0.f;
            float b1n = (-(wta * d) >= 1.f) ? 1.f : 0.f;
            w0 |= (unsigned)(unsigned char)(b1p * b13[o][p]) << (8 * p);
            w1 |= (unsigned)(unsigned char)(b1p * b24[o][p]) << (8 * p);  // G_INH = 1.0
            w2 |= (unsigned)(unsigned char)(b1n * b24[o][p]) << (8 * p);
            w3 |= (unsigned)(unsigned char)(b1n * b13[o][p]) << (8 * p);  // G_INH = 1.0
        }
        size_t base = (((size_t)b * 16 + 4 * o) * HH + gy) * WW + gxbase;
        *(unsigned*)&border[base]                      = w0;
        *(unsigned*)&border[base + (size_t)HH * WW]    = w1;
        *(unsigned*)&border[base + (size_t)2 * HH * WW] = w2;
        *(unsigned*)&border[base + (size_t)3 * HH * WW] = w3;
    }
}

// ---------------- Stage 2: depthwise 23x23 conv, one (batch,channel) plane per block ------
// Tile 32x128 out, thread = 4x * 4y. px=lx*4 -> b128 lane starts hit all 8 bank-quads
// (conflict-free); liveness acc[16]+a[28] ~= 55 VGPR -> no compiler LDS re-reads.
#define K2 23
#define PAD2 11
#define T2X 32
#define T2Y 128
#define S2C 56         // LDS cols: global x = tx0-12+col, col 0..55
#define R2 150         // staged rows: ty0-11 .. ty0+138

__global__ __launch_bounds__(256, 4) void stage2_kernel(
    const unsigned char* __restrict__ border, const float* __restrict__ Wg,
    unsigned char* __restrict__ gsp)
{
    __shared__ __align__(16) float tile[R2 * S2C];   // 33.6 KB -> 4 blocks/CU

    const int z   = blockIdx.z;
    const int b   = z >> 4;
    const int c   = z & 15;
    const int tx0 = blockIdx.x * T2X;
    const int ty0 = blockIdx.y * T2Y;
    const unsigned char* bp = border + ((size_t)b * 16 + c) * (HH * WW);

    // ---- stage u8 -> f32 tile: rows ty0-11.., cols tx0-12.. (4-byte aligned groups) ----
    for (int i = threadIdx.x; i < R2 * (S2C / 4); i += 256) {
        int iy = i / (S2C / 4), c4 = i - iy * (S2C / 4);
        int gy  = ty0 - PAD2 + iy;
        int gx0 = tx0 - 12 + 4 * c4;
        float4 f;
        bool rowok = (unsigned)gy < HH;
        if (rowok & ((unsigned)gx0 < WW)) {      // gx0 % 4 == 0, so gx0<512 => gx0+3<512
            unsigned u = *(const unsigned*)(bp + (size_t)gy * WW + gx0);
            f.x = (float)(u & 255u);
            f.y = (float)((u >> 8) & 255u);
            f.z = (float)((u >> 16) & 255u);
            f.w = (float)(u >> 24);
        } else if (rowok) {
            const unsigned char* rowp = bp + (size_t)gy * WW;
            f.x = ((unsigned)(gx0 + 0) < WW) ? (float)rowp[gx0 + 0] : 0.f;
            f.y = ((unsigned)(gx0 + 1) < WW) ? (float)rowp[gx0 + 1] : 0.f;
            f.z = ((unsigned)(gx0 + 2) < WW) ? (float)rowp[gx0 + 2] : 0.f;
            f.w = ((unsigned)(gx0 + 3) < WW) ? (float)rowp[gx0 + 3] : 0.f;
        } else {
            f.x = f.y = f.z = f.w = 0.f;
        }
        *(float4*)&tile[iy * S2C + 4 * c4] = f;
    }
    __syncthreads();

    const int lx = threadIdx.x & 7;    // 8 x-groups of 4 px -> 32 wide
    const int ly = threadIdx.x >> 3;   // 32 y-groups of 4 rows -> 128 tall
    const int px = lx * 4;
    const int py = ly * 4;

    float acc[4][4];
    #pragma unroll
    for (int dy = 0; dy < 4; dy++)
        #pragma unroll
        for (int p = 0; p < 4; p++) acc[dy][p] = 0.f;

    const float* wc = Wg + c * (K2 * K2);

    #pragma unroll 1
    for (int t = 0; t < 26; t++) {
        // one row window, read once, feeds up to 4 accumulator rows
        const float4* rp = (const float4*)&tile[(py + t) * S2C + px];
        float a[28];
        #pragma unroll
        for (int r = 0; r < 7; r++) *(float4*)&a[4 * r] = rp[r];
        #pragma unroll
        for (int dy = 0; dy < 4; dy++) {
            const int ky = t - dy;
            if (ky >= 0 && ky < K2) {            // wave-uniform branch
                const float* wr = wc + ky * K2;  // uniform -> s_load
                #pragma unroll
                for (int kx = 0; kx < K2; kx++) {
                    const float wv = wr[kx];
                    #pragma unroll
                    for (int p = 0; p < 4; p++)
                        acc[dy][p] = fmaf(a[kx + p + 1], wv, acc[dy][p]);
                }
            }
        }
    }

    // ---- spike + write u8 plane ----
    const int ox = tx0 + px;
    unsigned char* gp = gsp + ((size_t)b * 16 + c) * (HH * WW);
    #pragma unroll
    for (int dy = 0; dy < 4; dy++) {
        const int oy = ty0 + py + dy;
        unsigned w = 0;
        #pragma unroll
        for (int p = 0; p < 4; p++) w |= (acc[dy][p] >= 1.f ? 1u : 0u) << (8 * p);
        *(unsigned*)&gp[(size_t)oy * WW + ox] = w;
    }
}

// ---------------- Stage 3: combine 16 spike planes -> output ----------------
__global__ __launch_bounds__(256) void combine_kernel(
    const unsigned char* __restrict__ gsp, float* __restrict__ out)
{
    const int idx = blockIdx.x * 256 + threadIdx.x;   // 0 .. 4*65536-1 (uint granules)
    const int b = idx >> 16;
    const int r = idx & 65535;
    const unsigned* g = (const unsigned*)gsp;
    const int pb = b * 16;
    unsigned s = 0;
    #pragma unroll
    for (int o = 0; o < 4; o++) {
        unsigned g0 = g[(size_t)(pb + 4 * o + 0) * 65536 + r];
        unsigned g1 = g[(size_t)(pb + 4 * o + 1) * 65536 + r];
        unsigned g2 = g[(size_t)(pb + 4 * o + 2) * 65536 + r];
        unsigned g3 = g[(size_t)(pb + 4 * o + 3) * 65536 + r];
        s += ((g0 & ~g1) & 0x01010101u) + ((g2 & ~g3) & 0x01010101u);
    }
    float4 f;
    f.x = (float)(s & 255u);
    f.y = (float)((s >> 8) & 255u);
    f.z = (float)((s >> 16) & 255u);
    f.w = (float)(s >> 24);
    ((float4*)out)[idx] = f;
}

extern "C" void kernel_launch(void* const* d_in, const int* in_sizes, int n_in,
                              void* d_out, int out_size, void* d_ws, size_t ws_size,
                              hipStream_t stream)
{
    const float* inp = (const float*)d_in[0];   // (4,2,512,512) f32
    const float* Wb  = (const float*)d_in[1];   // (8,1,11,11)   f32
    const float* Wg  = (const float*)d_in[2];   // (16,1,23,23)  f32
    unsigned char* border = (unsigned char*)d_ws;                       // 16.78 MB
    unsigned char* gsp    = border + (size_t)NB * 16 * HH * WW;         // +16.78 MB
    float* out = (float*)d_out;                 // (4,512,512)   f32

    dim3 blk(256);
    dim3 g1(WW / T1, HH / T1, NB);          // 16x16x4 = 1024 blocks
    stage1_kernel<<<g1, blk, 0, stream>>>(inp, Wb, border);
    dim3 g2(WW / T2X, HH / T2Y, NB * 16);   // 16x4x64 = 4096 blocks
    stage2_kernel<<<g2, blk, 0, stream>>>(border, Wg, gsp);
    dim3 g3((NB * HH * WW / 4) / 256);      // 1024 blocks
    combine_kernel<<<g3, blk, 0, stream>>>(gsp, out);
}

// Round 6
// 330.211 us; speedup vs baseline: 1.0532x; 1.0532x over previous
//
#include <hip/hip_runtime.h>

#define HH 512
#define WW 512
#define NB 4

// ---------------- Stage 1: 11x11 convs (1->8, pos & neg) + spike/WTA logic ----------------
// 4 passes (2 planes x 4-channel halves); per ky the 16-wide window is consumed in
// three 8-float chunks so peak liveness ~= acc(16)+window(12) -> no compiler remat.
#define K1 11
#define PAD1 5
#define T1 32
#define IN1 42        // 32 + 10 halo
#define S1 44         // LDS row stride (floats)

__device__ __forceinline__ unsigned conv4_s1(const float* __restrict__ sm,
                                             const float* __restrict__ Wb,
                                             int py, int px, int cbase)
{
    float acc[4][4];
    #pragma unroll
    for (int cc = 0; cc < 4; cc++)
        #pragma unroll
        for (int p = 0; p < 4; p++) acc[cc][p] = 0.f;

    #pragma unroll 1
    for (int ky = 0; ky < K1; ky++) {
        const float* rowbase = &sm[(py + ky) * S1 + px];
        float a[8];
        *(float4*)&a[0] = *(const float4*)(rowbase + 0);
        *(float4*)&a[4] = *(const float4*)(rowbase + 4);
        #pragma unroll
        for (int cc = 0; cc < 4; cc++) {
            const float* wr = Wb + (cbase + cc) * (K1 * K1) + ky * K1;  // uniform -> s_load
            #pragma unroll
            for (int kx = 0; kx < 4; kx++) {
                const float wv = wr[kx];
                #pragma unroll
                for (int p = 0; p < 4; p++) acc[cc][p] = fmaf(a[kx + p], wv, acc[cc][p]);
            }
        }
        float b[8];
        *(float4*)&b[0] = *(float4*)&a[4];
        *(float4*)&b[4] = *(const float4*)(rowbase + 8);
        #pragma unroll
        for (int cc = 0; cc < 4; cc++) {
            const float* wr = Wb + (cbase + cc) * (K1 * K1) + ky * K1;
            #pragma unroll
            for (int kx = 4; kx < 8; kx++) {
                const float wv = wr[kx];
                #pragma unroll
                for (int p = 0; p < 4; p++) acc[cc][p] = fmaf(b[kx - 4 + p], wv, acc[cc][p]);
            }
        }
        float c2[8];
        *(float4*)&c2[0] = *(float4*)&b[4];
        *(float4*)&c2[4] = *(const float4*)(rowbase + 12);
        #pragma unroll
        for (int cc = 0; cc < 4; cc++) {
            const float* wr = Wb + (cbase + cc) * (K1 * K1) + ky * K1;
            #pragma unroll
            for (int kx = 8; kx < 11; kx++) {
                const float wv = wr[kx];
                #pragma unroll
                for (int p = 0; p < 4; p++) acc[cc][p] = fmaf(c2[kx - 8 + p], wv, acc[cc][p]);
            }
        }
    }
    unsigned bits = 0;
    #pragma unroll
    for (int cc = 0; cc < 4; cc++)
        #pragma unroll
        for (int p = 0; p < 4; p++)
            bits |= (acc[cc][p] >= 1.f ? 1u : 0u) << (cc * 4 + p);
    return bits;
}

__global__ __launch_bounds__(256, 4) void stage1_kernel(
    const float* __restrict__ inp, const float* __restrict__ Wb,
    unsigned char* __restrict__ border)
{
    __shared__ __align__(16) float s0[IN1 * S1];
    __shared__ __align__(16) float s1[IN1 * S1];

    const int b   = blockIdx.z;
    const int tx0 = blockIdx.x * T1;
    const int ty0 = blockIdx.y * T1;
    const float* in0 = inp + ((size_t)b * 2 + 0) * (HH * WW);
    const float* in1 = inp + ((size_t)b * 2 + 1) * (HH * WW);

    for (int i = threadIdx.x; i < IN1 * IN1; i += 256) {
        int iy = i / IN1, ix = i - iy * IN1;
        int gy = ty0 + iy - PAD1, gx = tx0 + ix - PAD1;
        bool ok = (gy >= 0) & (gy < HH) & (gx >= 0) & (gx < WW);
        int idx = gy * WW + gx;
        s0[iy * S1 + ix] = ok ? in0[idx] : 0.f;
        s1[iy * S1 + ix] = ok ? in1[idx] : 0.f;
    }
    __syncthreads();

    const int lx = threadIdx.x & 7;   // 8 groups of 4 px -> 32 wide
    const int ly = threadIdx.x >> 3;  // 32 rows
    const int px = lx * 4;
    const int py = ly;

    unsigned bitP = conv4_s1(s0, Wb, py, px, 0)
                  | (conv4_s1(s0, Wb, py, px, 4) << 16);
    unsigned bitN = conv4_s1(s1, Wb, py, px, 0)
                  | (conv4_s1(s1, Wb, py, px, 4) << 16);

    // ---- spike / WTA logic from bitmasks ----
    const int gy = ty0 + py;
    const int gxbase = tx0 + px;

    float vm[4];
    #pragma unroll
    for (int p = 0; p < 4; p++)
        vm[p] = s0[(py + PAD1) * S1 + px + PAD1 + p]
              + s1[(py + PAD1) * S1 + px + PAD1 + p];

    float b13[4][4], b24[4][4];       // [o][p]
    #pragma unroll
    for (int o = 0; o < 4; o++) {
        #pragma unroll
        for (int p = 0; p < 4; p++) {
            float pe = (float)((bitP >> (8 * o + p))     & 1u);
            float po = (float)((bitP >> (8 * o + 4 + p)) & 1u);
            float ne = (float)((bitN >> (8 * o + p))     & 1u);
            float no = (float)((bitN >> (8 * o + 4 + p)) & 1u);
            float sa = (vm[p] * (pe - 1.5f * no) >= 1.f) ? 1.f : 0.f;
            float sb = (vm[p] * (ne - 1.5f * po) >= 1.f) ? 1.f : 0.f;
            b13[o][p] = sa + sb;
            float sc = (vm[p] * (po - 1.5f * ne) >= 1.f) ? 1.f : 0.f;
            float sd = (vm[p] * (no - 1.5f * pe) >= 1.f) ? 1.f : 0.f;
            b24[o][p] = sc + sd;
        }
    }
    float mxp[4];
    #pragma unroll
    for (int p = 0; p < 4; p++) {
        float m = 0.f;
        #pragma unroll
        for (int o = 0; o < 4; o++) m = fmaxf(m, fabsf(b13[o][p] - b24[o][p]));
        mxp[p] = m;
    }
    #pragma unroll
    for (int o = 0; o < 4; o++) {
        unsigned w0 = 0, w1 = 0, w2 = 0, w3 = 0;
        #pragma unroll
        for (int p = 0; p < 4; p++) {
            float d   = b13[o][p] - b24[o][p];
            float wta = (fabsf(d) == mxp[p]) ? 1.f : 0.f;
            float b1p = (wta * d >= 1.f)    ? 1.f : 0.f;
            float b1n = (-(wta * d) >= 1.f) ? 1.f : 0.f;
            w0 |= (unsigned)(unsigned char)(b1p * b13[o][p]) << (8 * p);
            w1 |= (unsigned)(unsigned char)(b1p * b24[o][p]) << (8 * p);  // G_INH = 1.0
            w2 |= (unsigned)(unsigned char)(b1n * b24[o][p]) << (8 * p);
            w3 |= (unsigned)(unsigned char)(b1n * b13[o][p]) << (8 * p);  // G_INH = 1.0
        }
        size_t base = (((size_t)b * 16 + 4 * o) * HH + gy) * WW + gxbase;
        *(unsigned*)&border[base]                       = w0;
        *(unsigned*)&border[base + (size_t)HH * WW]     = w1;
        *(unsigned*)&border[base + (size_t)2 * HH * WW] = w2;
        *(unsigned*)&border[base + (size_t)3 * HH * WW] = w3;
    }
}

// bit layout note: conv4_s1(cbase=0) gives channels 0..3 in bits 0..15, cbase=4 gives
// channels 4..7 in bits 16..31; channel c = 2*o + (e/o), so (8*o+p)=even ch, (8*o+4+p)=odd.

// ---------------- Stage 2: depthwise 23x23 conv, one (batch,channel) plane per block ------
// Tile 32x128 out, thread = 4x * 4y; per t the 28-float window is consumed in two
// kx-chunks (peak live ~= 36 regs) so the compiler never re-reads LDS.
#define K2 23
#define PAD2 11
#define T2X 32
#define T2Y 128
#define S2C 56         // LDS cols: global x = tx0-12+col
#define R2 150         // staged rows: ty0-11 .. ty0+138

__global__ __launch_bounds__(256, 4) void stage2_kernel(
    const unsigned char* __restrict__ border, const float* __restrict__ Wg,
    unsigned char* __restrict__ gsp)
{
    __shared__ __align__(16) float tile[R2 * S2C];   // 33.6 KB -> 4 blocks/CU

    const int z   = blockIdx.z;
    const int b   = z >> 4;
    const int c   = z & 15;
    const int tx0 = blockIdx.x * T2X;
    const int ty0 = blockIdx.y * T2Y;
    const unsigned char* bp = border + ((size_t)b * 16 + c) * (HH * WW);

    // ---- stage u8 -> f32 tile ----
    for (int i = threadIdx.x; i < R2 * (S2C / 4); i += 256) {
        int iy = i / (S2C / 4), c4 = i - iy * (S2C / 4);
        int gy  = ty0 - PAD2 + iy;
        int gx0 = tx0 - 12 + 4 * c4;
        float4 f;
        bool rowok = (unsigned)gy < HH;
        if (rowok & ((unsigned)gx0 < WW)) {
            unsigned u = *(const unsigned*)(bp + (size_t)gy * WW + gx0);
            f.x = (float)(u & 255u);
            f.y = (float)((u >> 8) & 255u);
            f.z = (float)((u >> 16) & 255u);
            f.w = (float)(u >> 24);
        } else if (rowok) {
            const unsigned char* rowp = bp + (size_t)gy * WW;
            f.x = ((unsigned)(gx0 + 0) < WW) ? (float)rowp[gx0 + 0] : 0.f;
            f.y = ((unsigned)(gx0 + 1) < WW) ? (float)rowp[gx0 + 1] : 0.f;
            f.z = ((unsigned)(gx0 + 2) < WW) ? (float)rowp[gx0 + 2] : 0.f;
            f.w = ((unsigned)(gx0 + 3) < WW) ? (float)rowp[gx0 + 3] : 0.f;
        } else {
            f.x = f.y = f.z = f.w = 0.f;
        }
        *(float4*)&tile[iy * S2C + 4 * c4] = f;
    }
    __syncthreads();

    const int lx = threadIdx.x & 7;    // 8 x-groups of 4 px -> 32 wide
    const int ly = threadIdx.x >> 3;   // 32 y-groups of 4 rows -> 128 tall
    const int px = lx * 4;
    const int py = ly * 4;

    float acc[4][4];
    #pragma unroll
    for (int dy = 0; dy < 4; dy++)
        #pragma unroll
        for (int p = 0; p < 4; p++) acc[dy][p] = 0.f;

    const float* wc = Wg + c * (K2 * K2);

    #pragma unroll 1
    for (int t = 0; t < 26; t++) {
        const float* rowbase = &tile[(py + t) * S2C + px];
        // chunk 0: window a[0..15], taps kx 0..11 (uses a[1..15])
        float a[16];
        *(float4*)&a[0]  = *(const float4*)(rowbase + 0);
        *(float4*)&a[4]  = *(const float4*)(rowbase + 4);
        *(float4*)&a[8]  = *(const float4*)(rowbase + 8);
        *(float4*)&a[12] = *(const float4*)(rowbase + 12);
        #pragma unroll
        for (int dy = 0; dy < 4; dy++) {
            const int ky = t - dy;
            if (ky >= 0 && ky < K2) {            // wave-uniform
                const float* wr = wc + ky * K2;  // uniform -> s_load
                #pragma unroll
                for (int kx = 0; kx < 12; kx++) {
                    const float wv = wr[kx];
                    #pragma unroll
                    for (int p = 0; p < 4; p++)
                        acc[dy][p] = fmaf(a[kx + p + 1], wv, acc[dy][p]);
                }
            }
        }
        // chunk 1: window b[0..15] = a[12..27], taps kx 12..22 (uses b[1..14])
        float bb[16];
        *(float4*)&bb[0]  = *(float4*)&a[12];
        *(float4*)&bb[4]  = *(const float4*)(rowbase + 16);
        *(float4*)&bb[8]  = *(const float4*)(rowbase + 20);
        *(float4*)&bb[12] = *(const float4*)(rowbase + 24);
        #pragma unroll
        for (int dy = 0; dy < 4; dy++) {
            const int ky = t - dy;
            if (ky >= 0 && ky < K2) {
                const float* wr = wc + ky * K2;
                #pragma unroll
                for (int kx = 12; kx < 23; kx++) {
                    const float wv = wr[kx];
                    #pragma unroll
                    for (int p = 0; p < 4; p++)
                        acc[dy][p] = fmaf(bb[kx + p - 11], wv, acc[dy][p]);
                }
            }
        }
    }

    // ---- spike + write u8 plane ----
    const int ox = tx0 + px;
    unsigned char* gp = gsp + ((size_t)b * 16 + c) * (HH * WW);
    #pragma unroll
    for (int dy = 0; dy < 4; dy++) {
        const int oy = ty0 + py + dy;
        unsigned w = 0;
        #pragma unroll
        for (int p = 0; p < 4; p++) w |= (acc[dy][p] >= 1.f ? 1u : 0u) << (8 * p);
        *(unsigned*)&gp[(size_t)oy * WW + ox] = w;
    }
}

// ---------------- Stage 3: combine 16 spike planes -> output ----------------
__global__ __launch_bounds__(256) void combine_kernel(
    const unsigned char* __restrict__ gsp, float* __restrict__ out)
{
    const int idx = blockIdx.x * 256 + threadIdx.x;   // uint granules
    const int b = idx >> 16;
    const int r = idx & 65535;
    const unsigned* g = (const unsigned*)gsp;
    const int pb = b * 16;
    unsigned s = 0;
    #pragma unroll
    for (int o = 0; o < 4; o++) {
        unsigned g0 = g[(size_t)(pb + 4 * o + 0) * 65536 + r];
        unsigned g1 = g[(size_t)(pb + 4 * o + 1) * 65536 + r];
        unsigned g2 = g[(size_t)(pb + 4 * o + 2) * 65536 + r];
        unsigned g3 = g[(size_t)(pb + 4 * o + 3) * 65536 + r];
        s += ((g0 & ~g1) & 0x01010101u) + ((g2 & ~g3) & 0x01010101u);
    }
    float4 f;
    f.x = (float)(s & 255u);
    f.y = (float)((s >> 8) & 255u);
    f.z = (float)((s >> 16) & 255u);
    f.w = (float)(s >> 24);
    ((float4*)out)[idx] = f;
}

extern "C" void kernel_launch(void* const* d_in, const int* in_sizes, int n_in,
                              void* d_out, int out_size, void* d_ws, size_t ws_size,
                              hipStream_t stream)
{
    const float* inp = (const float*)d_in[0];   // (4,2,512,512) f32
    const float* Wb  = (const float*)d_in[1];   // (8,1,11,11)   f32
    const float* Wg  = (const float*)d_in[2];   // (16,1,23,23)  f32
    unsigned char* border = (unsigned char*)d_ws;                       // 16.78 MB
    unsigned char* gsp    = border + (size_t)NB * 16 * HH * WW;         // +16.78 MB
    float* out = (float*)d_out;                 // (4,512,512)   f32

    dim3 blk(256);
    dim3 g1(WW / T1, HH / T1, NB);          // 16x16x4 = 1024 blocks
    stage1_kernel<<<g1, blk, 0, stream>>>(inp, Wb, border);
    dim3 g2(WW / T2X, HH / T2Y, NB * 16);   // 16x4x64 = 4096 blocks
    stage2_kernel<<<g2, blk, 0, stream>>>(border, Wg, gsp);
    dim3 g3((NB * HH * WW / 4) / 256);      // 1024 blocks
    combine_kernel<<<g3, blk, 0, stream>>>(gsp, out);
}

// Round 7
// 289.728 us; speedup vs baseline: 1.2004x; 1.1397x over previous
//
#include <hip/hip_runtime.h>

#define HH 512
#define WW 512
#define NB 4

// ---------------- Stage 1: 11x11 convs (1->8, pos & neg) + spike/WTA logic ----------------
// One ky-loop per channel-half; weights (44/ky) hoisted to SGPRs and shared by P and N
// planes. Liveness: accP16+accN16+window16 ~= 48 VGPR.
#define K1 11
#define PAD1 5
#define T1 32
#define IN1 42        // 32 + 10 halo
#define S1 44         // LDS row stride (floats)

__global__ __launch_bounds__(256, 4) void stage1_kernel(
    const float* __restrict__ inp, const float* __restrict__ Wb,
    unsigned char* __restrict__ border)
{
    __shared__ __align__(16) float s0[IN1 * S1];
    __shared__ __align__(16) float s1[IN1 * S1];

    const int b   = blockIdx.z;
    const int tx0 = blockIdx.x * T1;
    const int ty0 = blockIdx.y * T1;
    const float* in0 = inp + ((size_t)b * 2 + 0) * (HH * WW);
    const float* in1 = inp + ((size_t)b * 2 + 1) * (HH * WW);

    for (int i = threadIdx.x; i < IN1 * IN1; i += 256) {
        int iy = i / IN1, ix = i - iy * IN1;
        int gy = ty0 + iy - PAD1, gx = tx0 + ix - PAD1;
        bool ok = (gy >= 0) & (gy < HH) & (gx >= 0) & (gx < WW);
        int idx = gy * WW + gx;
        s0[iy * S1 + ix] = ok ? in0[idx] : 0.f;
        s1[iy * S1 + ix] = ok ? in1[idx] : 0.f;
    }
    __syncthreads();

    const int lx = threadIdx.x & 7;   // 8 groups of 4 px -> 32 wide
    const int ly = threadIdx.x >> 3;  // 32 rows
    const int px = lx * 4;
    const int py = ly;

    unsigned bitP = 0, bitN = 0;

    #pragma unroll
    for (int half = 0; half < 2; half++) {       // static cb => static weight indices
        const int cb = half * 4;
        float aP[4][4], aN[4][4];
        #pragma unroll
        for (int cc = 0; cc < 4; cc++)
            #pragma unroll
            for (int p = 0; p < 4; p++) { aP[cc][p] = 0.f; aN[cc][p] = 0.f; }

        #pragma unroll 1
        for (int ky = 0; ky < K1; ky++) {
            {   // plane P
                const float4* rp = (const float4*)&s0[(py + ky) * S1 + px];
                float a[16];
                #pragma unroll
                for (int r = 0; r < 4; r++) *(float4*)&a[4 * r] = rp[r];
                #pragma unroll
                for (int cc = 0; cc < 4; cc++) {
                    #pragma unroll
                    for (int kx = 0; kx < K1; kx++) {
                        const float wv = Wb[(cb + cc) * 121 + ky * 11 + kx]; // uniform s_load
                        #pragma unroll
                        for (int p = 0; p < 4; p++)
                            aP[cc][p] = fmaf(a[kx + p], wv, aP[cc][p]);
                    }
                }
            }
            {   // plane N (same weights, already in SGPRs)
                const float4* rp = (const float4*)&s1[(py + ky) * S1 + px];
                float a[16];
                #pragma unroll
                for (int r = 0; r < 4; r++) *(float4*)&a[4 * r] = rp[r];
                #pragma unroll
                for (int cc = 0; cc < 4; cc++) {
                    #pragma unroll
                    for (int kx = 0; kx < K1; kx++) {
                        const float wv = Wb[(cb + cc) * 121 + ky * 11 + kx];
                        #pragma unroll
                        for (int p = 0; p < 4; p++)
                            aN[cc][p] = fmaf(a[kx + p], wv, aN[cc][p]);
                    }
                }
            }
        }
        #pragma unroll
        for (int cc = 0; cc < 4; cc++)
            #pragma unroll
            for (int p = 0; p < 4; p++) {
                bitP |= (aP[cc][p] >= 1.f ? 1u : 0u) << (16 * half + cc * 4 + p);
                bitN |= (aN[cc][p] >= 1.f ? 1u : 0u) << (16 * half + cc * 4 + p);
            }
    }

    // ---- spike / WTA logic from bitmasks (identical to verified round-6 code) ----
    const int gy = ty0 + py;
    const int gxbase = tx0 + px;

    float vm[4];
    #pragma unroll
    for (int p = 0; p < 4; p++)
        vm[p] = s0[(py + PAD1) * S1 + px + PAD1 + p]
              + s1[(py + PAD1) * S1 + px + PAD1 + p];

    float b13[4][4], b24[4][4];       // [o][p]
    #pragma unroll
    for (int o = 0; o < 4; o++) {
        #pragma unroll
        for (int p = 0; p < 4; p++) {
            float pe = (float)((bitP >> (8 * o + p))     & 1u);
            float po = (float)((bitP >> (8 * o + 4 + p)) & 1u);
            float ne = (float)((bitN >> (8 * o + p))     & 1u);
            float no = (float)((bitN >> (8 * o + 4 + p)) & 1u);
            float sa = (vm[p] * (pe - 1.5f * no) >= 1.f) ? 1.f : 0.f;
            float sb = (vm[p] * (ne - 1.5f * po) >= 1.f) ? 1.f : 0.f;
            b13[o][p] = sa + sb;
            float sc = (vm[p] * (po - 1.5f * ne) >= 1.f) ? 1.f : 0.f;
            float sd = (vm[p] * (no - 1.5f * pe) >= 1.f) ? 1.f : 0.f;
            b24[o][p] = sc + sd;
        }
    }
    float mxp[4];
    #pragma unroll
    for (int p = 0; p < 4; p++) {
        float m = 0.f;
        #pragma unroll
        for (int o = 0; o < 4; o++) m = fmaxf(m, fabsf(b13[o][p] - b24[o][p]));
        mxp[p] = m;
    }
    #pragma unroll
    for (int o = 0; o < 4; o++) {
        unsigned w0 = 0, w1 = 0, w2 = 0, w3 = 0;
        #pragma unroll
        for (int p = 0; p < 4; p++) {
            float d   = b13[o][p] - b24[o][p];
            float wta = (fabsf(d) == mxp[p]) ? 1.f : 0.f;
            float b1p = (wta * d >= 1.f)    ? 1.f : 0.f;
            float b1n = (-(wta * d) >= 1.f) ? 1.f : 0.f;
            w0 |= (unsigned)(unsigned char)(b1p * b13[o][p]) << (8 * p);
            w1 |= (unsigned)(unsigned char)(b1p * b24[o][p]) << (8 * p);  // G_INH = 1.0
            w2 |= (unsigned)(unsigned char)(b1n * b24[o][p]) << (8 * p);
            w3 |= (unsigned)(unsigned char)(b1n * b13[o][p]) << (8 * p);  // G_INH = 1.0
        }
        size_t base = (((size_t)b * 16 + 4 * o) * HH + gy) * WW + gxbase;
        *(unsigned*)&border[base]                       = w0;
        *(unsigned*)&border[base + (size_t)HH * WW]     = w1;
        *(unsigned*)&border[base + (size_t)2 * HH * WW] = w2;
        *(unsigned*)&border[base + (size_t)3 * HH * WW] = w3;
    }
}

// ---------------- Stage 2: depthwise 23x23 conv, u8 LDS tile + ky-blocking ----------------
// Thread = 8 px (x) * 2 rows (y); tile 32x128. Tile stays u8 in LDS (4x fewer DS bytes,
// conflicts moot; stride 72 B spreads ly over banks). Taps processed in ky-blocks of 3 so
// the 69 block weights hoist into SGPRs once (no per-row SMEM refetch).
#define K2 23
#define PAD2 11
#define T2X 32
#define T2Y 128
#define SROW 18        // LDS row stride in dwords (72 B): 72*row -> bank term 4*ly (uniform)
#define R2 150         // staged rows: ty0-11 .. ty0+138

__device__ __forceinline__ float ubyte_f(unsigned dw, int byi) {
    return (float)((dw >> (8 * byi)) & 0xffu);   // -> v_cvt_f32_ubyteN
}

__global__ __launch_bounds__(256, 4) void stage2_kernel(
    const unsigned char* __restrict__ border, const float* __restrict__ Wg,
    unsigned char* __restrict__ gsp)
{
    __shared__ unsigned tile[R2 * SROW];   // u8 tile, 10.8 KB

    const int z   = blockIdx.z;
    const int b   = z >> 4;
    const int c   = z & 15;
    const int tx0 = blockIdx.x * T2X;
    const int ty0 = blockIdx.y * T2Y;
    const unsigned char* bp = border + ((size_t)b * 16 + c) * (HH * WW);

    // ---- stage u8 rows [ty0-11, ty0+139), cols [tx0-12, tx0+52) as dwords ----
    for (int i = threadIdx.x; i < R2 * 16; i += 256) {
        int iy = i >> 4, cc = i & 15;
        int gy  = ty0 - PAD2 + iy;
        int gx0 = tx0 - 12 + 4 * cc;       // 4-aligned; in range iff 0<=gx0<=508
        unsigned u = 0;
        if (((unsigned)gy < HH) & ((unsigned)gx0 < WW))
            u = *(const unsigned*)(bp + (size_t)gy * WW + gx0);
        tile[iy * SROW + cc] = u;
    }
    __syncthreads();

    const int lx = threadIdx.x & 3;    // 4 x-groups of 8 px -> 32 wide
    const int ly = threadIdx.x >> 2;   // 64 y-groups of 2 rows -> 128 tall
    const int px = lx * 8;
    const int py = ly * 2;

    float acc[2][8];
    #pragma unroll
    for (int dy = 0; dy < 2; dy++)
        #pragma unroll
        for (int p = 0; p < 8; p++) acc[dy][p] = 0.f;

    const float* wc = Wg + c * (K2 * K2);

    // 7 full ky-blocks of 3 taps, then a tail block of 2 (ky 21,22)
    #pragma unroll 1
    for (int kyb = 0; kyb < 7; kyb++) {
        const int b0 = kyb * 3;
        #pragma unroll
        for (int r = 0; r < 4; r++) {                  // input rows py+b0+r
            const int trow = py + b0 + r;
            unsigned d[8];
            const uint2* tp2 = (const uint2*)&tile[trow * SROW + 2 * lx];
            #pragma unroll
            for (int r2 = 0; r2 < 4; r2++) { uint2 v = tp2[r2]; d[2*r2] = v.x; d[2*r2+1] = v.y; }
            float a[31];
            #pragma unroll
            for (int j = 1; j <= 30; j++) a[j] = ubyte_f(d[j >> 2], j & 3);
            #pragma unroll
            for (int jk = 0; jk < 3; jk++) {
                const int dy = r - jk;
                if (dy >= 0 && dy < 2) {               // compile-time after unroll
                    #pragma unroll
                    for (int kx = 0; kx < 23; kx++) {
                        const float wv = wc[(b0 + jk) * 23 + kx];   // uniform -> s_load, CSEd
                        #pragma unroll
                        for (int p = 0; p < 8; p++)
                            acc[dy][p] = fmaf(a[p + kx + 1], wv, acc[dy][p]);
                    }
                }
            }
        }
    }
    {   // tail: ky 21,22
        const int b0 = 21;
        #pragma unroll
        for (int r = 0; r < 3; r++) {
            const int trow = py + b0 + r;
            unsigned d[8];
            const uint2* tp2 = (const uint2*)&tile[trow * SROW + 2 * lx];
            #pragma unroll
            for (int r2 = 0; r2 < 4; r2++) { uint2 v = tp2[r2]; d[2*r2] = v.x; d[2*r2+1] = v.y; }
            float a[31];
            #pragma unroll
            for (int j = 1; j <= 30; j++) a[j] = ubyte_f(d[j >> 2], j & 3);
            #pragma unroll
            for (int jk = 0; jk < 2; jk++) {
                const int dy = r - jk;
                if (dy >= 0 && dy < 2) {
                    #pragma unroll
                    for (int kx = 0; kx < 23; kx++) {
                        const float wv = wc[(b0 + jk) * 23 + kx];
                        #pragma unroll
                        for (int p = 0; p < 8; p++)
                            acc[dy][p] = fmaf(a[p + kx + 1], wv, acc[dy][p]);
                    }
                }
            }
        }
    }

    // ---- spike + write u8 plane ----
    const int ox = tx0 + px;               // multiple of 8 -> uint2 store OK
    unsigned char* gp = gsp + ((size_t)b * 16 + c) * (HH * WW);
    #pragma unroll
    for (int dy = 0; dy < 2; dy++) {
        const int oy = ty0 + py + dy;
        unsigned lo = 0, hi = 0;
        #pragma unroll
        for (int p = 0; p < 4; p++) lo |= (acc[dy][p]     >= 1.f ? 1u : 0u) << (8 * p);
        #pragma unroll
        for (int p = 0; p < 4; p++) hi |= (acc[dy][p + 4] >= 1.f ? 1u : 0u) << (8 * p);
        uint2 v; v.x = lo; v.y = hi;
        *(uint2*)&gp[(size_t)oy * WW + ox] = v;
    }
}

// ---------------- Stage 3: combine 16 spike planes -> output ----------------
__global__ __launch_bounds__(256) void combine_kernel(
    const unsigned char* __restrict__ gsp, float* __restrict__ out)
{
    const int idx = blockIdx.x * 256 + threadIdx.x;   // uint granules
    const int b = idx >> 16;
    const int r = idx & 65535;
    const unsigned* g = (const unsigned*)gsp;
    const int pb = b * 16;
    unsigned s = 0;
    #pragma unroll
    for (int o = 0; o < 4; o++) {
        unsigned g0 = g[(size_t)(pb + 4 * o + 0) * 65536 + r];
        unsigned g1 = g[(size_t)(pb + 4 * o + 1) * 65536 + r];
        unsigned g2 = g[(size_t)(pb + 4 * o + 2) * 65536 + r];
        unsigned g3 = g[(size_t)(pb + 4 * o + 3) * 65536 + r];
        s += ((g0 & ~g1) & 0x01010101u) + ((g2 & ~g3) & 0x01010101u);
    }
    float4 f;
    f.x = (float)(s & 255u);
    f.y = (float)((s >> 8) & 255u);
    f.z = (float)((s >> 16) & 255u);
    f.w = (float)(s >> 24);
    ((float4*)out)[idx] = f;
}

extern "C" void kernel_launch(void* const* d_in, const int* in_sizes, int n_in,
                              void* d_out, int out_size, void* d_ws, size_t ws_size,
                              hipStream_t stream)
{
    const float* inp = (const float*)d_in[0];   // (4,2,512,512) f32
    const float* Wb  = (const float*)d_in[1];   // (8,1,11,11)   f32
    const float* Wg  = (const float*)d_in[2];   // (16,1,23,23)  f32
    unsigned char* border = (unsigned char*)d_ws;                       // 16.78 MB
    unsigned char* gsp    = border + (size_t)NB * 16 * HH * WW;         // +16.78 MB
    float* out = (float*)d_out;                 // (4,512,512)   f32

    dim3 blk(256);
    dim3 g1(WW / T1, HH / T1, NB);          // 16x16x4 = 1024 blocks
    stage1_kernel<<<g1, blk, 0, stream>>>(inp, Wb, border);
    dim3 g2(WW / T2X, HH / T2Y, NB * 16);   // 16x4x64 = 4096 blocks
    stage2_kernel<<<g2, blk, 0, stream>>>(border, Wg, gsp);
    dim3 g3((NB * HH * WW / 4) / 256);      // 1024 blocks
    combine_kernel<<<g3, blk, 0, stream>>>(gsp, out);
}